// Round 2
// baseline (178.593 us; speedup 1.0000x reference)
//
#include <hip/hip_runtime.h>
#include <cstdint>

#define NB 64
#define NC 256
#define ND 256
#define NT 4096

#define BT 64                    // t-columns per tile
#define NTILES 16                // tiles per block
#define CHUNK (BT * NTILES)      // 1024 t per block
#define NCHUNK (NT / CHUNK)      // 4 chunks

typedef __attribute__((ext_vector_type(8)))  _Float16 half8;
typedef __attribute__((ext_vector_type(16))) float    f32x16;

union FragA { uint32_t u[4]; uint4 q; half8 v; };

__device__ __forceinline__ uint32_t pk_f16(float lo, float hi) {
    // v_cvt_pkrtz_f16_f32: D.lo=f16(lo), D.hi=f16(hi) — matches MFMA (k even, k odd) packing
    return __builtin_bit_cast(uint32_t, __builtin_amdgcn_cvt_pkrtz(lo, hi));
}

// LDS layout (per buffer): fp16 x-tile, [t=0..63][c=0..255], row = 512 B.
// byte(t, c) = t*512 + ( (2*c) ^ ((t&15)<<4) )   — XOR swizzle on 16B columns,
// applied identically on write and read (involution within each 512B row).
__global__ __launch_bounds__(1024)
void subject_gemm(const float* __restrict__ x,
                  const int*   __restrict__ subjects,
                  const float* __restrict__ w,
                  float*       __restrict__ out)
{
    __shared__ __align__(16) unsigned char lds[2 * 64 * 512];   // 64 KiB, double-buffered

    const int tid  = threadIdx.x;
    const int lane = tid & 63;
    const int wv   = tid >> 6;      // 0..15
    const int wd   = wv & 7;        // d-range (32 d per wave)
    const int wm   = wv >> 3;       // t-half (32 t per wave)
    const int g    = lane >> 5;     // k-group
    const int l31  = lane & 31;
    const int b    = blockIdx.y;
    const int t0   = blockIdx.x * CHUNK;

    const int sub = subjects[b];
    const float* __restrict__ wsub = w + (size_t)sub * NC * ND;
    const float* __restrict__ xb   = x + (size_t)b * NC * NT;
    float*       __restrict__ ob   = out + (size_t)b * ND * NT;

    const int dlane = wd * 32 + l31;

    // ---- one-time: W B-fragments (fp16) in registers ----
    // B[k][n] for mfma_f32_32x32x16_f16: n = lane&31, k = 8*(lane>>5)+j
    half8 wf[16];
#pragma unroll
    for (int ks = 0; ks < 16; ++ks) {
        float f[8];
#pragma unroll
        for (int j = 0; j < 8; ++j)
            f[j] = wsub[(size_t)(ks * 16 + g * 8 + j) * ND + dlane];
        FragA tmp;
#pragma unroll
        for (int p = 0; p < 4; ++p) tmp.u[p] = pk_f16(f[2 * p], f[2 * p + 1]);
        wf[ks] = tmp.v;
    }

    // ---- staging assignment: wave wv owns c in [wv*16, wv*16+16), lane = t ----
    const int cbase = wv * 16;
    const uint32_t wr_swz   = ((uint32_t)(lane & 15)) << 4;
    const uint32_t wr_byte0 = (uint32_t)lane * 512 + (((uint32_t)cbase * 2 +  0) ^ wr_swz);
    const uint32_t wr_byte1 = (uint32_t)lane * 512 + (((uint32_t)cbase * 2 + 16) ^ wr_swz);

    // read-side constants: t_local = wm*32 + l31
    const int      trd    = wm * 32 + l31;
    const uint32_t rd_swz = ((uint32_t)(trd & 15)) << 4;
    const uint32_t rd_row = (uint32_t)trd * 512;

    const float* xg = xb + (size_t)cbase * NT + t0 + lane;   // + i*NT + tile*BT

    float stage[16];

    // prologue: stage tile 0
#pragma unroll
    for (int i = 0; i < 16; ++i) stage[i] = xg[(size_t)i * NT];
    {
        uint4 q0, q1;
        q0.x = pk_f16(stage[0],  stage[1]);  q0.y = pk_f16(stage[2],  stage[3]);
        q0.z = pk_f16(stage[4],  stage[5]);  q0.w = pk_f16(stage[6],  stage[7]);
        q1.x = pk_f16(stage[8],  stage[9]);  q1.y = pk_f16(stage[10], stage[11]);
        q1.z = pk_f16(stage[12], stage[13]); q1.w = pk_f16(stage[14], stage[15]);
        *reinterpret_cast<uint4*>(&lds[wr_byte0]) = q0;
        *reinterpret_cast<uint4*>(&lds[wr_byte1]) = q1;
    }
    __syncthreads();

    for (int tile = 0; tile < NTILES; ++tile) {
        const uint32_t bufoff = (uint32_t)(tile & 1) * 32768;

        // T14: issue next tile's global loads now; consume after compute
        if (tile + 1 < NTILES) {
            const float* src = xg + (size_t)(tile + 1) * BT;
#pragma unroll
            for (int i = 0; i < 16; ++i) stage[i] = src[(size_t)i * NT];
        }

        // ---- compute: one 32x32 tile per wave, K=256 in 16 MFMA steps ----
        f32x16 acc = {};
#pragma unroll
        for (int ks = 0; ks < 16; ++ks) {
            const uint32_t colb = ((uint32_t)(ks * 32 + g * 16)) ^ rd_swz;
            FragA a;
            a.q = *reinterpret_cast<const uint4*>(&lds[bufoff + rd_row + colb]);
            acc = __builtin_amdgcn_mfma_f32_32x32x16_f16(a.v, wf[ks], acc, 0, 0, 0);
        }

        // ---- store: C/D layout col=lane&31=d, row=(reg&3)+8*(reg>>2)+4*g = t ----
        const int tb = t0 + tile * BT + wm * 32;
#pragma unroll
        for (int rg = 0; rg < 4; ++rg) {
            const int trow = tb + rg * 8 + g * 4;
            float4 vv = make_float4(acc[4 * rg + 0], acc[4 * rg + 1],
                                    acc[4 * rg + 2], acc[4 * rg + 3]);
            *reinterpret_cast<float4*>(&ob[(size_t)dlane * NT + trow]) = vv;
        }

        // convert + write staged tile into the other buffer (loads have landed by now)
        if (tile + 1 < NTILES) {
            const uint32_t nb = (uint32_t)((tile + 1) & 1) * 32768;
            uint4 q0, q1;
            q0.x = pk_f16(stage[0],  stage[1]);  q0.y = pk_f16(stage[2],  stage[3]);
            q0.z = pk_f16(stage[4],  stage[5]);  q0.w = pk_f16(stage[6],  stage[7]);
            q1.x = pk_f16(stage[8],  stage[9]);  q1.y = pk_f16(stage[10], stage[11]);
            q1.z = pk_f16(stage[12], stage[13]); q1.w = pk_f16(stage[14], stage[15]);
            *reinterpret_cast<uint4*>(&lds[nb + wr_byte0]) = q0;
            *reinterpret_cast<uint4*>(&lds[nb + wr_byte1]) = q1;
        }
        __syncthreads();
    }
}

extern "C" void kernel_launch(void* const* d_in, const int* in_sizes, int n_in,
                              void* d_out, int out_size, void* d_ws, size_t ws_size,
                              hipStream_t stream)
{
    const float* x        = (const float*)d_in[0];
    const int*   subjects = (const int*)d_in[1];
    const float* w        = (const float*)d_in[2];
    float*       out      = (float*)d_out;

    dim3 grid(NCHUNK, NB);   // 4 x 64 = 256 blocks, 1024 threads, 64 KiB LDS
    subject_gemm<<<grid, 1024, 0, stream>>>(x, subjects, w, out);
}